// Round 13
// baseline (379.400 us; speedup 1.0000x reference)
//
#include <hip/hip_runtime.h>

#define NPIX 9216
#define NL   21
#define WW   96
#define RAD  16
#define JS   16
#define NJC  576            // NPIX / JS
#define NST  9              // NJC / 64
#define NIB  72             // NPIX / 128 i-blocks
#define NBIL (NIB * JS)     // 1152 bilat blocks
#define NSXY 252            // 21 labels x 12 bands
#define L2E  1.44269504088896340736f

typedef __bf16 bf16x8 __attribute__((ext_vector_type(8)));
typedef float  f32x16 __attribute__((ext_vector_type(16)));

__device__ __forceinline__ float fexp2(float x) { return __builtin_amdgcn_exp2f(x); }
__device__ __forceinline__ unsigned pkbf(float lo, float hi) {
    unsigned r;
    asm("v_cvt_pk_bf16_f32 %0, %1, %2" : "=v"(r) : "v"(lo), "v"(hi));
    return r;
}

// ---------- prep: bf16 feature fragments + truncated spatial norm + QhT const rows + zero Bl ----------
__global__ __launch_bounds__(256) void featK(const float* __restrict__ img,
                                             __bf16* __restrict__ FiT8, __bf16* __restrict__ Fj8,
                                             float* __restrict__ norm_s, __bf16* __restrict__ QhT,
                                             float* __restrict__ Bl) {
    int i = blockIdx.x * 256 + threadIdx.x;
    if (i >= NPIX) return;
    int y = i / WW, x = i - y * WW;
    float f0 = (float)x * (1.0f / 160.0f);
    float f1 = (float)y * (1.0f / 160.0f);
    float f2 = img[0 * NPIX + i] * (1.0f / 3.0f);
    float f3 = img[1 * NPIX + i] * (1.0f / 3.0f);
    float f4 = img[2 * NPIX + i] * (1.0f / 3.0f);
    float st = 0.5f * (f0*f0 + f1*f1 + f2*f2 + f3*f3 + f4*f4) * L2E;
    __bf16* a = Fj8 + (size_t)i * 16;
    __bf16* b = FiT8 + (size_t)i * 16;
    a[0]=(__bf16)(f0*L2E); a[1]=(__bf16)(f1*L2E); a[2]=(__bf16)(f2*L2E);
    a[3]=(__bf16)(f3*L2E); a[4]=(__bf16)(f4*L2E); a[5]=(__bf16)st; a[6]=(__bf16)1.0f;
    b[0]=(__bf16)f0; b[1]=(__bf16)f1; b[2]=(__bf16)f2; b[3]=(__bf16)f3; b[4]=(__bf16)f4;
    b[5]=(__bf16)-1.0f; b[6]=(__bf16)(-st);
    #pragma unroll
    for (int k = 7; k < 16; k++) { a[k] = (__bf16)0.0f; b[k] = (__bf16)0.0f; }
    QhT[(size_t)21 * NPIX + i] = (__bf16)1.0f;
    #pragma unroll
    for (int l = 22; l < 32; l++) QhT[(size_t)l * NPIX + i] = (__bf16)0.0f;
    #pragma unroll
    for (int l = 0; l < 22; l++) Bl[(size_t)l * NPIX + i] = 0.0f;
    const float cs = (-0.5f / 9.0f) * L2E;
    float sx = 0.f, sy = 0.f;
    int xa = max(0, x - RAD), xb = min(WW - 1, x + RAD);
    int ya = max(0, y - RAD), yb = min(WW - 1, y + RAD);
    for (int t = xa; t <= xb; t++) { float dx = (float)(x - t); sx += fexp2(cs * dx * dx); }
    for (int t = ya; t <= yb; t++) { float dy = (float)(y - t); sy += fexp2(cs * dy * dy); }
    norm_s[i] = 1.0f / (sx * sy + 1e-8f);
}

// ---------- fold 21x21 matrices ----------
__global__ __launch_bounds__(448) void matK(const float* __restrict__ Cm, const float* __restrict__ Wsm,
                                            const float* __restrict__ Wbm,
                                            float* __restrict__ Ms, float* __restrict__ Mb) {
    int t = threadIdx.x;
    if (t >= NL * NL) return;
    int l = t / NL, p = t - l * NL;
    float a = 0.f, b = 0.f;
    for (int m = 0; m < NL; m++) {
        float c = Cm[l * NL + m];
        a = fmaf(c, Wsm[m * NL + p], a);
        b = fmaf(c, Wbm[m * NL + p], b);
    }
    Ms[t] = a; Mb[t] = b;
}

// ---------- iter-0 softmax -> QhT only ----------
__global__ __launch_bounds__(256) void smax0(const float* __restrict__ cur, __bf16* __restrict__ QhT) {
    int i = blockIdx.x * 256 + threadIdx.x;
    if (i >= NPIX) return;
    float v[NL]; float m = -1e30f;
    #pragma unroll
    for (int l = 0; l < NL; l++) { v[l] = cur[l * NPIX + i]; m = fmaxf(m, v[l]); }
    float s = 0.f;
    #pragma unroll
    for (int l = 0; l < NL; l++) { v[l] = fexp2((v[l] - m) * L2E); s += v[l]; }
    float inv = 1.0f / s;
    #pragma unroll
    for (int l = 0; l < NL; l++) QhT[(size_t)l * NPIX + i] = (__bf16)(v[l] * inv);
}

// ---------- fused: bilat (blocks 0..NBIL-1, atomic Bl) | spatXY (blocks NBIL..NBIL+NSXY-1) ----------
// spatXY block = (label l, 8-row band): x-pass (incl. +-16 halo rows) into LDS, y-pass -> Sp.
__global__ __launch_bounds__(256) void fusedAll(const __bf16* __restrict__ QhT,
                                                const __bf16* __restrict__ FiT8,
                                                const __bf16* __restrict__ Fj8,
                                                float* __restrict__ Bl,
                                                const float* __restrict__ norm_s,
                                                float* __restrict__ Sp) {
    __shared__ __align__(16) unsigned char smem[15872];
    int t = threadIdx.x;

    if (blockIdx.x >= NBIL) {
        // ---- spatXY branch ----
        float* S1t = (float*)smem;             // [<=40][96]
        float* wt  = (float*)(smem + 15360);   // [33]
        int bid = blockIdx.x - NBIL;
        int l = bid / 12, band = bid - l * 12;
        int y0 = band * 8;
        int ya = max(0, y0 - RAD), yb = min(WW - 1, y0 + 7 + RAD);
        int cnt = yb - ya + 1;                 // <= 40
        if (t < 33) { float d = (float)(t - RAD); wt[t] = fexp2((-0.5f / 9.0f) * L2E * d * d); }
        __syncthreads();
        const __bf16* qbase = QhT + (size_t)l * NPIX;
        for (int idx = t; idx < cnt * WW; idx += 256) {
            int yy = idx / WW, x1 = idx - yy * WW;
            const __bf16* row = qbase + (ya + yy) * WW;
            float acc = 0.f;
            #pragma unroll
            for (int d = 0; d < 33; d++) {
                int x2 = x1 - RAD + d;
                if ((unsigned)x2 < WW) acc = fmaf(wt[d], (float)row[x2], acc);
            }
            S1t[idx] = acc;
        }
        __syncthreads();
        for (int idx = t; idx < 8 * WW; idx += 256) {
            int r = idx / WW, x = idx - r * WW;
            int y1 = y0 + r;
            float acc = 0.f;
            #pragma unroll
            for (int d = 0; d < 33; d++) {
                int y2 = y1 - RAD + d;
                if ((unsigned)y2 < WW) acc = fmaf(wt[d], S1t[(y2 - ya) * WW + x], acc);
            }
            int gi = y1 * WW + x;
            Sp[(size_t)l * NPIX + gi] = acc * norm_s[gi];
        }
        return;
    }

    // ---- bilat branch (attention-style, atomic accumulate into Bl) ----
    __bf16* sQ  = (__bf16*)smem;            // [2][32][72]
    __bf16* sFj = (__bf16*)(smem + 9216);   // [2][64][24]
    int lane = t & 63;
    int w = t >> 6;
    int n = lane & 31, kb = lane >> 5;
    int jc = blockIdx.x / NIB;
    int ib = blockIdx.x - jc * NIB;
    int ibase = ib * 128 + w * 32;

    bf16x8 b1 = *reinterpret_cast<const bf16x8*>(FiT8 + (size_t)(ibase + n) * 16 + kb * 8);

    int qr = t >> 3, qc = t & 7;          // sQ: 32 rows x 8 float4 chunks
    int fr = t >> 1, fh = t & 1;          // sFj: 64 rows x 2 float4 (threads < 128)
    int jbeg = jc * NJC;
    const __bf16* qsrc = QhT + (size_t)qr * NPIX + jbeg;
    const __bf16* fsrc = Fj8 + (size_t)jbeg * 16;

    float4 gq = *reinterpret_cast<const float4*>(qsrc + qc * 8);
    float4 gf;
    if (t < 128) gf = *reinterpret_cast<const float4*>(fsrc + fr * 16 + fh * 8);
    *reinterpret_cast<float4*>(sQ + (size_t)qr * 72 + qc * 8) = gq;
    if (t < 128) *reinterpret_cast<float4*>(sFj + (size_t)fr * 24 + fh * 8) = gf;

    f32x16 acc = {};
    const f32x16 z = {};
    int cur = 0;
    for (int s = 0; s < NST; s++) {
        __syncthreads();
        bool pf = (s + 1 < NST);
        if (pf) {
            int jo = (s + 1) * 64;
            gq = *reinterpret_cast<const float4*>(qsrc + jo + qc * 8);
            if (t < 128) gf = *reinterpret_cast<const float4*>(fsrc + (size_t)(jo + fr) * 16 + fh * 8);
        }
        #pragma unroll
        for (int t2 = 0; t2 < 2; t2++) {
            int t32 = t2 * 32;
            bf16x8 a1 = *reinterpret_cast<const bf16x8*>(sFj + ((size_t)cur * 64 + t32 + n) * 24 + kb * 8);
            f32x16 d = __builtin_amdgcn_mfma_f32_32x32x16_bf16(a1, b1, z, 0, 0, 0);
            float e[16];
            #pragma unroll
            for (int q = 0; q < 16; q++) e[q] = fexp2(d[q]);
            #pragma unroll
            for (int h = 0; h < 2; h++) {
                unsigned w0 = pkbf(e[8*h+0], e[8*h+1]);
                unsigned w1 = pkbf(e[8*h+2], e[8*h+3]);
                unsigned w2 = pkbf(e[8*h+4], e[8*h+5]);
                unsigned w3 = pkbf(e[8*h+6], e[8*h+7]);
                asm volatile("v_permlane32_swap_b32 %0, %1" : "+v"(w0), "+v"(w2));
                asm volatile("v_permlane32_swap_b32 %0, %1" : "+v"(w1), "+v"(w3));
                union { int4 u4; bf16x8 h8; } bb;
                bb.u4 = make_int4(w0, w1, w2, w3);
                bf16x8 qa = *reinterpret_cast<const bf16x8*>(sQ + ((size_t)cur * 32 + n) * 72 + t32 + h * 16 + kb * 8);
                acc = __builtin_amdgcn_mfma_f32_32x32x16_bf16(qa, bb.h8, acc, 0, 0, 0);
            }
        }
        if (pf) {
            int nx = cur ^ 1;
            *reinterpret_cast<float4*>(sQ + ((size_t)nx * 32 + qr) * 72 + qc * 8) = gq;
            if (t < 128) *reinterpret_cast<float4*>(sFj + ((size_t)nx * 64 + fr) * 24 + fh * 8) = gf;
        }
        cur ^= 1;
    }
    int gi = ibase + n;
    #pragma unroll
    for (int q = 0; q < 16; q++) {
        int l = (q & 3) + 8 * (q >> 2) + 4 * kb;   // verified C/D row map
        if (l < 22) atomicAdd(&Bl[(size_t)l * NPIX + gi], acc[q]);
    }
}

// ---------- combine + bilateral norm + re-zero Bl + softmax -> QhT ----------
__global__ __launch_bounds__(256) void combZ(const float* __restrict__ Sp, float* __restrict__ Bl,
                                             const float* __restrict__ Ms, const float* __restrict__ Mb,
                                             const float* __restrict__ unary, float* __restrict__ outp,
                                             __bf16* __restrict__ QhT, int wq) {
    __shared__ float sMs[NL * NL], sMb[NL * NL];
    int t = threadIdx.x;
    for (int k = t; k < NL * NL; k += 256) { sMs[k] = Ms[k]; sMb[k] = Mb[k]; }
    __syncthreads();
    int i = blockIdx.x * 256 + t;
    if (i >= NPIX) return;
    float inv = 1.0f / (Bl[(size_t)21 * NPIX + i] + 1e-8f);
    float sp[NL], bl[NL], v[NL];
    #pragma unroll
    for (int p = 0; p < NL; p++) { sp[p] = Sp[p * NPIX + i]; bl[p] = Bl[p * NPIX + i] * inv; }
    #pragma unroll
    for (int l = 0; l < 22; l++) Bl[(size_t)l * NPIX + i] = 0.0f;   // ready for next bilat
    #pragma unroll
    for (int l = 0; l < NL; l++) {
        float a = unary[l * NPIX + i];
        #pragma unroll
        for (int p = 0; p < NL; p++) {
            a = fmaf(sMs[l * NL + p], sp[p], a);
            a = fmaf(sMb[l * NL + p], bl[p], a);
        }
        outp[l * NPIX + i] = a;
        v[l] = a;
    }
    if (!wq) return;
    float m = -1e30f;
    #pragma unroll
    for (int l = 0; l < NL; l++) m = fmaxf(m, v[l]);
    float s = 0.f;
    #pragma unroll
    for (int l = 0; l < NL; l++) { v[l] = fexp2((v[l] - m) * L2E); s += v[l]; }
    float qi = 1.0f / s;
    #pragma unroll
    for (int l = 0; l < NL; l++) QhT[(size_t)l * NPIX + i] = (__bf16)(v[l] * qi);
}

extern "C" void kernel_launch(void* const* d_in, const int* in_sizes, int n_in,
                              void* d_out, int out_size, void* d_ws, size_t ws_size,
                              hipStream_t stream) {
    const float* img   = (const float*)d_in[0];
    const float* logit = (const float*)d_in[1];
    const float* Wsm   = (const float*)d_in[2];
    const float* Wbm   = (const float*)d_in[3];
    const float* Cm    = (const float*)d_in[4];
    float* out = (float*)d_out;
    float* ws  = (float*)d_ws;

    // workspace layout (float offsets)
    __bf16* FiT8  = (__bf16*)ws;              // [0, 73728)
    __bf16* Fj8   = (__bf16*)(ws + 73728);    // [73728, 147456)
    float* Sp     = ws + 147456;              // [147456, 340992)
    float* Bl     = ws + 340992;              // [340992, 543744)  22 rows
    float* norm_s = ws + 543744;              // [543744, 552960)
    float* Ms     = ws + 552960;              // [552960, 553408)
    float* Mb     = ws + 553408;              // [553408, 553856)
    __bf16* QhT   = (__bf16*)(ws + 553856);   // [553856, 701312)  32*NPIX bf16 = 147456 floats

    featK<<<36, 256, 0, stream>>>(img, FiT8, Fj8, norm_s, QhT, Bl);
    matK<<<1, 448, 0, stream>>>(Cm, Wsm, Wbm, Ms, Mb);
    smax0<<<36, 256, 0, stream>>>(logit, QhT);
    for (int it = 0; it < 5; ++it) {
        fusedAll<<<NBIL + NSXY, 256, 0, stream>>>(QhT, FiT8, Fj8, Bl, norm_s, Sp);
        combZ<<<36, 256, 0, stream>>>(Sp, Bl, Ms, Mb, logit, out, QhT, it < 4 ? 1 : 0);
    }
}

// Round 14
// 218.139 us; speedup vs baseline: 1.7393x; 1.7393x over previous
//
#include <hip/hip_runtime.h>

#define NPIX 9216
#define NL   21
#define WW   96
#define RAD  16
#define JS   16
#define NJC  576            // NPIX / JS
#define NST  9              // NJC / 64
#define NIB  72             // NPIX / 128 i-blocks
#define NBIL (NIB * JS)     // 1152 bilat blocks
#define NSPT 756            // NL*NPIX / 256 spatial blocks
#define L2E  1.44269504088896340736f

typedef __bf16 bf16x8 __attribute__((ext_vector_type(8)));
typedef float  f32x16 __attribute__((ext_vector_type(16)));

__device__ __forceinline__ float fexp2(float x) { return __builtin_amdgcn_exp2f(x); }
__device__ __forceinline__ unsigned pkbf(float lo, float hi) {
    unsigned r;
    asm("v_cvt_pk_bf16_f32 %0, %1, %2" : "=v"(r) : "v"(lo), "v"(hi));
    return r;
}

// ---------- prep: bf16 feature fragments + truncated spatial norm + QhT const rows + zero Bl ----------
__global__ __launch_bounds__(256) void featK(const float* __restrict__ img,
                                             __bf16* __restrict__ FiT8, __bf16* __restrict__ Fj8,
                                             float* __restrict__ norm_s, __bf16* __restrict__ QhT,
                                             float* __restrict__ Bl) {
    int i = blockIdx.x * 256 + threadIdx.x;
    if (i >= NPIX) return;
    int y = i / WW, x = i - y * WW;
    float f0 = (float)x * (1.0f / 160.0f);
    float f1 = (float)y * (1.0f / 160.0f);
    float f2 = img[0 * NPIX + i] * (1.0f / 3.0f);
    float f3 = img[1 * NPIX + i] * (1.0f / 3.0f);
    float f4 = img[2 * NPIX + i] * (1.0f / 3.0f);
    float st = 0.5f * (f0*f0 + f1*f1 + f2*f2 + f3*f3 + f4*f4) * L2E;
    __bf16* a = Fj8 + (size_t)i * 16;
    __bf16* b = FiT8 + (size_t)i * 16;
    a[0]=(__bf16)(f0*L2E); a[1]=(__bf16)(f1*L2E); a[2]=(__bf16)(f2*L2E);
    a[3]=(__bf16)(f3*L2E); a[4]=(__bf16)(f4*L2E); a[5]=(__bf16)st; a[6]=(__bf16)1.0f;
    b[0]=(__bf16)f0; b[1]=(__bf16)f1; b[2]=(__bf16)f2; b[3]=(__bf16)f3; b[4]=(__bf16)f4;
    b[5]=(__bf16)-1.0f; b[6]=(__bf16)(-st);
    #pragma unroll
    for (int k = 7; k < 16; k++) { a[k] = (__bf16)0.0f; b[k] = (__bf16)0.0f; }
    QhT[(size_t)21 * NPIX + i] = (__bf16)1.0f;
    #pragma unroll
    for (int l = 22; l < 32; l++) QhT[(size_t)l * NPIX + i] = (__bf16)0.0f;
    #pragma unroll
    for (int l = 0; l < 22; l++) Bl[(size_t)l * NPIX + i] = 0.0f;
    const float cs = (-0.5f / 9.0f) * L2E;
    float sx = 0.f, sy = 0.f;
    int xa = max(0, x - RAD), xb = min(WW - 1, x + RAD);
    int ya = max(0, y - RAD), yb = min(WW - 1, y + RAD);
    for (int t = xa; t <= xb; t++) { float dx = (float)(x - t); sx += fexp2(cs * dx * dx); }
    for (int t = ya; t <= yb; t++) { float dy = (float)(y - t); sy += fexp2(cs * dy * dy); }
    norm_s[i] = 1.0f / (sx * sy + 1e-8f);
}

// ---------- fold 21x21 matrices ----------
__global__ __launch_bounds__(448) void matK(const float* __restrict__ Cm, const float* __restrict__ Wsm,
                                            const float* __restrict__ Wbm,
                                            float* __restrict__ Ms, float* __restrict__ Mb) {
    int t = threadIdx.x;
    if (t >= NL * NL) return;
    int l = t / NL, p = t - l * NL;
    float a = 0.f, b = 0.f;
    for (int m = 0; m < NL; m++) {
        float c = Cm[l * NL + m];
        a = fmaf(c, Wsm[m * NL + p], a);
        b = fmaf(c, Wbm[m * NL + p], b);
    }
    Ms[t] = a; Mb[t] = b;
}

// ---------- iter-0 softmax -> QhT only ----------
__global__ __launch_bounds__(256) void smax0(const float* __restrict__ cur, __bf16* __restrict__ QhT) {
    int i = blockIdx.x * 256 + threadIdx.x;
    if (i >= NPIX) return;
    float v[NL]; float m = -1e30f;
    #pragma unroll
    for (int l = 0; l < NL; l++) { v[l] = cur[l * NPIX + i]; m = fmaxf(m, v[l]); }
    float s = 0.f;
    #pragma unroll
    for (int l = 0; l < NL; l++) { v[l] = fexp2((v[l] - m) * L2E); s += v[l]; }
    float inv = 1.0f / s;
    #pragma unroll
    for (int l = 0; l < NL; l++) QhT[(size_t)l * NPIX + i] = (__bf16)(v[l] * inv);
}

// ---------- spatial x-pass: reads bf16 QhT, one output/thread ----------
__global__ __launch_bounds__(256) void spatX(const __bf16* __restrict__ QhT, float* __restrict__ S1) {
    __shared__ float wt[33];
    int t = threadIdx.x;
    if (t < 33) { float d = (float)(t - RAD); wt[t] = fexp2((-0.5f / 9.0f) * L2E * d * d); }
    __syncthreads();
    int tid = blockIdx.x * 256 + t;                 // NL*NPIX exact (756 blocks)
    int l = tid / NPIX, rem = tid - l * NPIX;
    int y = rem / WW, x1 = rem - y * WW;
    const __bf16* row = QhT + (size_t)l * NPIX + y * WW;
    float acc = 0.f;
    #pragma unroll
    for (int d = 0; d < 33; d++) {
        int x2 = x1 - RAD + d;
        if ((unsigned)x2 < WW) acc = fmaf(wt[d], (float)row[x2], acc);
    }
    S1[tid] = acc;
}

// ---------- fused: bilat (blocks 0..NBIL-1, atomic Bl) | spatY (blocks NBIL..) ----------
__global__ __launch_bounds__(256) void fusedYB(const __bf16* __restrict__ QhT,
                                               const __bf16* __restrict__ FiT8,
                                               const __bf16* __restrict__ Fj8,
                                               float* __restrict__ Bl,
                                               const float* __restrict__ S1,
                                               const float* __restrict__ norm_s,
                                               float* __restrict__ Sp) {
    __shared__ __bf16 sQ[2][32][72];    // 9216 B
    __shared__ __bf16 sFj[2][64][24];   // 6144 B
    __shared__ float wt[33];
    int t = threadIdx.x;

    if (blockIdx.x >= NBIL) {
        // ---- spatY branch ----
        if (t < 33) { float d = (float)(t - RAD); wt[t] = fexp2((-0.5f / 9.0f) * L2E * d * d); }
        __syncthreads();
        int tid = (blockIdx.x - NBIL) * 256 + t;
        int l = tid / NPIX, rem = tid - l * NPIX;
        int y1 = rem / WW, x = rem - y1 * WW;
        const float* col = S1 + l * NPIX + x;
        float acc = 0.f;
        #pragma unroll
        for (int d = 0; d < 33; d++) {
            int y2 = y1 - RAD + d;
            if ((unsigned)y2 < WW) acc = fmaf(wt[d], col[y2 * WW], acc);
        }
        Sp[tid] = acc * norm_s[rem];
        return;
    }

    // ---- bilat branch ----
    int lane = t & 63;
    int w = t >> 6;
    int n = lane & 31, kb = lane >> 5;
    int jc = blockIdx.x / NIB;
    int ib = blockIdx.x - jc * NIB;
    int ibase = ib * 128 + w * 32;

    bf16x8 b1 = *reinterpret_cast<const bf16x8*>(FiT8 + (size_t)(ibase + n) * 16 + kb * 8);

    int qr = t >> 3, qc = t & 7;          // sQ: 32 rows x 8 float4 chunks
    int fr = t >> 1, fh = t & 1;          // sFj: 64 rows x 2 float4 (threads < 128)
    int jbeg = jc * NJC;
    const __bf16* qsrc = QhT + (size_t)qr * NPIX + jbeg;
    const __bf16* fsrc = Fj8 + (size_t)jbeg * 16;

    float4 gq = *reinterpret_cast<const float4*>(qsrc + qc * 8);
    float4 gf;
    if (t < 128) gf = *reinterpret_cast<const float4*>(fsrc + fr * 16 + fh * 8);
    *reinterpret_cast<float4*>(&sQ[0][qr][qc * 8]) = gq;
    if (t < 128) *reinterpret_cast<float4*>(&sFj[0][fr][fh * 8]) = gf;

    f32x16 acc = {};
    const f32x16 z = {};
    int cur = 0;
    for (int s = 0; s < NST; s++) {
        __syncthreads();
        bool pf = (s + 1 < NST);
        if (pf) {
            int jo = (s + 1) * 64;
            gq = *reinterpret_cast<const float4*>(qsrc + jo + qc * 8);
            if (t < 128) gf = *reinterpret_cast<const float4*>(fsrc + (size_t)(jo + fr) * 16 + fh * 8);
        }
        #pragma unroll
        for (int t2 = 0; t2 < 2; t2++) {
            int t32 = t2 * 32;
            bf16x8 a1 = *reinterpret_cast<const bf16x8*>(&sFj[cur][t32 + n][kb * 8]);
            f32x16 d = __builtin_amdgcn_mfma_f32_32x32x16_bf16(a1, b1, z, 0, 0, 0);
            float e[16];
            #pragma unroll
            for (int q = 0; q < 16; q++) e[q] = fexp2(d[q]);
            #pragma unroll
            for (int h = 0; h < 2; h++) {
                unsigned w0 = pkbf(e[8*h+0], e[8*h+1]);
                unsigned w1 = pkbf(e[8*h+2], e[8*h+3]);
                unsigned w2 = pkbf(e[8*h+4], e[8*h+5]);
                unsigned w3 = pkbf(e[8*h+6], e[8*h+7]);
                asm volatile("v_permlane32_swap_b32 %0, %1" : "+v"(w0), "+v"(w2));
                asm volatile("v_permlane32_swap_b32 %0, %1" : "+v"(w1), "+v"(w3));
                union { int4 u4; bf16x8 h8; } bb;
                bb.u4 = make_int4(w0, w1, w2, w3);
                bf16x8 qa = *reinterpret_cast<const bf16x8*>(&sQ[cur][n][t32 + h * 16 + kb * 8]);
                acc = __builtin_amdgcn_mfma_f32_32x32x16_bf16(qa, bb.h8, acc, 0, 0, 0);
            }
        }
        if (pf) {
            int nx = cur ^ 1;
            *reinterpret_cast<float4*>(&sQ[nx][qr][qc * 8]) = gq;
            if (t < 128) *reinterpret_cast<float4*>(&sFj[nx][fr][fh * 8]) = gf;
        }
        cur ^= 1;
    }
    int gi = ibase + n;
    #pragma unroll
    for (int q = 0; q < 16; q++) {
        int l = (q & 3) + 8 * (q >> 2) + 4 * kb;   // verified C/D row map
        if (l < 22) atomicAdd(&Bl[(size_t)l * NPIX + gi], acc[q]);
    }
}

// ---------- combine + bilateral norm + re-zero Bl + softmax -> QhT (144 x 64 wide grid) ----------
__global__ __launch_bounds__(64) void combZ(const float* __restrict__ Sp, float* __restrict__ Bl,
                                            const float* __restrict__ Ms, const float* __restrict__ Mb,
                                            const float* __restrict__ unary, float* __restrict__ outp,
                                            __bf16* __restrict__ QhT, int wq) {
    __shared__ float sMs[NL * NL], sMb[NL * NL];
    int t = threadIdx.x;
    for (int k = t; k < NL * NL; k += 64) { sMs[k] = Ms[k]; sMb[k] = Mb[k]; }
    __syncthreads();
    int i = blockIdx.x * 64 + t;
    if (i >= NPIX) return;
    float inv = 1.0f / (Bl[(size_t)21 * NPIX + i] + 1e-8f);
    float sp[NL], bl[NL], v[NL];
    #pragma unroll
    for (int p = 0; p < NL; p++) { sp[p] = Sp[p * NPIX + i]; bl[p] = Bl[p * NPIX + i] * inv; }
    #pragma unroll
    for (int l = 0; l < 22; l++) Bl[(size_t)l * NPIX + i] = 0.0f;   // ready for next bilat
    #pragma unroll
    for (int l = 0; l < NL; l++) {
        float a = unary[l * NPIX + i];
        #pragma unroll
        for (int p = 0; p < NL; p++) {
            a = fmaf(sMs[l * NL + p], sp[p], a);
            a = fmaf(sMb[l * NL + p], bl[p], a);
        }
        outp[l * NPIX + i] = a;
        v[l] = a;
    }
    if (!wq) return;
    float m = -1e30f;
    #pragma unroll
    for (int l = 0; l < NL; l++) m = fmaxf(m, v[l]);
    float s = 0.f;
    #pragma unroll
    for (int l = 0; l < NL; l++) { v[l] = fexp2((v[l] - m) * L2E); s += v[l]; }
    float qi = 1.0f / s;
    #pragma unroll
    for (int l = 0; l < NL; l++) QhT[(size_t)l * NPIX + i] = (__bf16)(v[l] * qi);
}

extern "C" void kernel_launch(void* const* d_in, const int* in_sizes, int n_in,
                              void* d_out, int out_size, void* d_ws, size_t ws_size,
                              hipStream_t stream) {
    const float* img   = (const float*)d_in[0];
    const float* logit = (const float*)d_in[1];
    const float* Wsm   = (const float*)d_in[2];
    const float* Wbm   = (const float*)d_in[3];
    const float* Cm    = (const float*)d_in[4];
    float* out = (float*)d_out;
    float* ws  = (float*)d_ws;

    // workspace layout (float offsets)
    __bf16* FiT8  = (__bf16*)ws;              // [0, 73728)
    __bf16* Fj8   = (__bf16*)(ws + 73728);    // [73728, 147456)
    float* S1     = ws + 147456;              // [147456, 340992)
    float* Sp     = ws + 340992;              // [340992, 534528)
    float* Bl     = ws + 534528;              // [534528, 737280)  22 rows
    float* norm_s = ws + 737280;              // [737280, 746496)
    float* Ms     = ws + 746496;              // [746496, 746944)
    float* Mb     = ws + 746944;              // [746944, 747392)
    __bf16* QhT   = (__bf16*)(ws + 747392);   // [747392, 894848)  32*NPIX bf16 = 147456 floats

    featK<<<36, 256, 0, stream>>>(img, FiT8, Fj8, norm_s, QhT, Bl);
    matK<<<1, 448, 0, stream>>>(Cm, Wsm, Wbm, Ms, Mb);
    smax0<<<36, 256, 0, stream>>>(logit, QhT);
    for (int it = 0; it < 5; ++it) {
        spatX<<<756, 256, 0, stream>>>(QhT, S1);
        fusedYB<<<NBIL + NSPT, 256, 0, stream>>>(QhT, FiT8, Fj8, Bl, S1, norm_s, Sp);
        combZ<<<144, 64, 0, stream>>>(Sp, Bl, Ms, Mb, logit, out, QhT, it < 4 ? 1 : 0);
    }
}